// Round 10
// baseline (71.829 us; speedup 1.0000x reference)
//
#include <hip/hip_runtime.h>
#include <math.h>

#define HW 262144            // 512*512
#define TOTAL 12582912       // 48 planes * HW
#define TS 32
#define NT 512               // threads per block
#define P 2                  // planes per block, element-interleaved as float2
#define NGROUP 24            // 48 / P

#define CR 0.8910065241883679f   // cos(27 deg)
#define SR 0.45399049973954675f  // sin(27 deg)

#define K5CX (255.5f * (1.0f - CR + SR))
#define K5CY (255.5f * (1.0f - SR - CR))

// Fixed padded region dims (>= max true span at any tile position)
#define W2 52
#define H2 44
#define W3 46
#define H3 45
#define W4 49
#define H4 48
#define W5 36
#define H5 35
#define BUFA_SZ 2352   // float2 cells: max(W2*H2=2288, W4*H4=2352)
#define BUFB_SZ 2070   // float2 cells: max(W3*H3=2070, W5*H5=1260)

struct Box { int x0, x1, y0, y1; };

__device__ __forceinline__ Box back_box(Box d, float A, float B, float C,
                                        float D, float E, float F) {
    float xa = (float)d.x0, xb = (float)d.x1, ya = (float)d.y0, yb = (float)d.y1;
    float mnx = fminf(A * xa, A * xb) + fminf(B * ya, B * yb) + C;
    float mxx = fmaxf(A * xa, A * xb) + fmaxf(B * ya, B * yb) + C;
    float mny = fminf(D * xa, D * xb) + fminf(E * ya, E * yb) + F;
    float mxy = fmaxf(D * xa, D * xb) + fmaxf(E * ya, E * yb) + F;
    Box s;
    s.x0 = (int)floorf(mnx); s.x1 = (int)floorf(mxx) + 1;
    s.y0 = (int)floorf(mny); s.y1 = (int)floorf(mxy) + 1;
    return s;
}

// ---- packed fp32 (CDNA double-rate) helpers: one instr processes both planes ----
__device__ __forceinline__ float2 pk_mul(float2 a, float2 b) {
    float2 r;
    asm("v_pk_mul_f32 %0, %1, %2" : "=v"(r) : "v"(a), "v"(b));
    return r;
}
__device__ __forceinline__ float2 pk_fma(float2 a, float2 b, float2 c) {
    float2 r;
    asm("v_pk_fma_f32 %0, %1, %2, %3" : "=v"(r) : "v"(a), "v"(b), "v"(c));
    return r;
}
// a + w*(b-a)  computed as  (w*b) + (a - w*a)   [2 pk instrs]
__device__ __forceinline__ float2 pk_lerp(float2 w2, float2 a, float2 b) {
    float2 t, r;
    asm("v_pk_fma_f32 %0, %1, %2, %2 neg_lo:[1,0,0] neg_hi:[1,0,0]"
        : "=v"(t) : "v"(w2), "v"(a));                       // t = a - w*a
    asm("v_pk_fma_f32 %0, %1, %2, %3"
        : "=v"(r) : "v"(w2), "v"(b), "v"(t));               // r = w*b + t
    return r;
}

// ---- stage 2 (translate, mirror folded): global -> bufA (float2), 2 planes ----
// Constant weights wx=0.36, wy=0.76; taps at x = 496-pxi, 495-pxi; rows pyi-11, pyi-10.
template <bool INT>
__device__ __forceinline__ void s2_eval(int i, const float* __restrict__ gin,
                                        float2* __restrict__ dst, int rx0, int ry0)
{
    int ly = i / W2;
    int lx = i - ly * W2;
    int pxi = rx0 + lx, pyi = ry0 + ly;
    if (INT) {
        const float2 C64 = {0.64f, 0.64f}, C36 = {0.36f, 0.36f};
        const float2 C24 = {0.24f, 0.24f}, C76 = {0.76f, 0.76f};
        int off = ((pyi - 11) << 9) + (496 - pxi);
        const float* g0 = gin + off;
        const float* g1 = gin + HW + off;
        // 8 independent loads, then plane-packed math (6 pk instrs)
        float2 v00 = {g0[0],   g1[0]};
        float2 v01 = {g0[-1],  g1[-1]};
        float2 v10 = {g0[512], g1[512]};
        float2 v11 = {g0[511], g1[511]};
        float2 h0 = pk_fma(C36, v01, pk_mul(C64, v00));
        float2 h1 = pk_fma(C36, v11, pk_mul(C64, v10));
        dst[i] = pk_fma(C76, h1, pk_mul(C24, h0));
    } else {
        float wx0m = ((unsigned)pxi <= 496u) ? 0.64f : 0.0f;
        float wx1m = ((unsigned)pxi <= 495u) ? 0.36f : 0.0f;
        float wy0m = ((unsigned)(pyi - 11) <= 500u) ? 0.24f : 0.0f;
        float wy1m = ((unsigned)(pyi - 10) <= 501u) ? 0.76f : 0.0f;
        int xc0 = min(max(496 - pxi, 0), 511);
        int xc1 = min(max(495 - pxi, 0), 511);
        int r0 = min(max(pyi - 11, 0), 511) << 9;
        int r1 = min(max(pyi - 10, 0), 511) << 9;
        float2 o;
        #pragma unroll
        for (int p = 0; p < P; ++p) {
            const float* g = gin + p * HW;
            float v00 = g[r0 + xc0], v01 = g[r0 + xc1];
            float v10 = g[r1 + xc0], v11 = g[r1 + xc1];
            float h0 = fmaf(wx1m, v01, wx0m * v00);
            float h1 = fmaf(wx1m, v11, wx0m * v10);
            float val = fmaf(wy1m, h1, wy0m * h0);
            if (p == 0) o.x = val; else o.y = val;
        }
        dst[i] = o;
    }
}

// ---- LDS -> LDS bilinear stage, both planes per float2 cell, packed math ----
template <int SW, int SH, int DW, bool AXIS, bool INT>
__device__ __forceinline__ void lds_eval(int i, float A, float B, float Cs,
    float D, float E, float Fs, const float2* __restrict__ src,
    float2* __restrict__ dst, int dx0, int dy0)
{
    int ly = i / DW;
    int lx = i - ly * DW;
    int pxi = dx0 + lx, pyi = dy0 + ly;
    float px = (float)pxi, py = (float)pyi;
    float fx = AXIS ? fmaf(A, px, Cs) : fmaf(A, px, fmaf(B, py, Cs));
    float fy = AXIS ? fmaf(E, py, Fs) : fmaf(D, px, fmaf(E, py, Fs));
    float xf = floorf(fx), yf = floorf(fy);
    float wx = fx - xf, wy = fy - yf;
    int x0 = (int)xf, y0 = (int)yf;
    if (!INT) { x0 = min(max(x0, 0), SW - 2); y0 = min(max(y0, 0), SH - 2); }
    const float2* s = src + y0 * SW + x0;
    float2 v00 = s[0], v01 = s[1];        // ds_read2_b64 pair
    float2 v10 = s[SW], v11 = s[SW + 1];
    float2 wx2 = {wx, wx}, wy2 = {wy, wy};
    float2 a0 = pk_lerp(wx2, v00, v01);
    float2 a1 = pk_lerp(wx2, v10, v11);
    float2 val = pk_lerp(wy2, a0, a1);
    if (!INT) {
        if ((unsigned)pxi >= 512u || (unsigned)pyi >= 512u) { val.x = 0.f; val.y = 0.f; }
    }
    dst[i] = val;                          // ds_write_b64
}

template <int SW, int SH, int DW, int DTOT, bool AXIS, bool INT>
__device__ __forceinline__ void stage_lds(int tid, float A, float B, float Cs,
    float D, float E, float Fs, const float2* __restrict__ src,
    float2* __restrict__ dst, int dx0, int dy0)
{
    constexpr int FULL = DTOT / NT;
    constexpr int TAIL = DTOT - FULL * NT;
    #pragma unroll
    for (int k = 0; k < FULL; ++k)
        lds_eval<SW, SH, DW, AXIS, INT>(tid + k * NT, A, B, Cs, D, E, Fs,
                                        src, dst, dx0, dy0);
    if (TAIL && tid < TAIL)
        lds_eval<SW, SH, DW, AXIS, INT>(tid + FULL * NT, A, B, Cs, D, E, Fs,
                                        src, dst, dx0, dy0);
}

// ---- stage 6 (shear): bufB(R5, float2) -> global, 2 planes, packed math ----
template <bool INT>
__device__ __forceinline__ void s6_eval(int ii, const float2* __restrict__ src,
    float* __restrict__ go, int tx0, int ty0, int sx0, int sy0)
{
    int lx = ii & 31, ly = ii >> 5;
    float px = (float)(tx0 + lx), py = (float)(ty0 + ly);
    float fx = fmaf(0.05f, py, -12.775f - (float)sx0) + px;
    float fy = fmaf(-0.03f, px, 7.665f - (float)sy0) + py;
    float xf = floorf(fx), yf = floorf(fy);
    float wx = fx - xf, wy = fy - yf;
    int x0 = (int)xf, y0 = (int)yf;
    if (!INT) { x0 = min(max(x0, 0), W5 - 2); y0 = min(max(y0, 0), H5 - 2); }
    const float2* s = src + y0 * W5 + x0;
    float2 v00 = s[0], v01 = s[1];
    float2 v10 = s[W5], v11 = s[W5 + 1];
    float2 wx2 = {wx, wx}, wy2 = {wy, wy};
    float2 a0 = pk_lerp(wx2, v00, v01);
    float2 a1 = pk_lerp(wx2, v10, v11);
    float2 val = pk_lerp(wy2, a0, a1);
    int gidx = (ty0 + ly) * 512 + tx0 + lx;
    __builtin_nontemporal_store(val.x, &go[gidx]);
    __builtin_nontemporal_store(val.y, &go[HW + gidx]);
}

// ---- full img tile pipeline for 2 interleaved planes ----
template <bool INT>
__device__ __forceinline__ void img_tile(int tid, const float* __restrict__ gin,
    float* __restrict__ go, int tx0, int ty0,
    Box R2, Box R3, Box R4, Box R5, float2* bufA, float2* bufB)
{
    // stage 2: global -> bufA(R2)
    {
        constexpr int FULL = (W2 * H2) / NT;
        constexpr int TAIL = W2 * H2 - FULL * NT;
        #pragma unroll
        for (int k = 0; k < FULL; ++k)
            s2_eval<INT>(tid + k * NT, gin, bufA, R2.x0, R2.y0);
        if (tid < TAIL) s2_eval<INT>(tid + FULL * NT, gin, bufA, R2.x0, R2.y0);
    }
    __syncthreads();
    // stage 3 (scale): bufA(R2) -> bufB(R3)
    stage_lds<W2, H2, W3, W3 * H3, true, INT>(tid,
        1.1f, 0.0f, -25.55f - (float)R2.x0,
        0.0f, 0.95f, 12.775f - (float)R2.y0, bufA, bufB, R3.x0, R3.y0);
    __syncthreads();
    // stage 4 (zoom): bufB(R3) -> bufA(R4)
    stage_lds<W3, H3, W4, W4 * H4, true, INT>(tid,
        0.9f, 0.0f, 25.55f - (float)R3.x0,
        0.0f, 0.9f, 25.55f - (float)R3.y0, bufB, bufA, R4.x0, R4.y0);
    __syncthreads();
    // stage 5 (rotate): bufA(R4) -> bufB(R5)
    stage_lds<W4, H4, W5, W5 * H5, false, INT>(tid,
        CR, -SR, K5CX - (float)R4.x0,
        SR,  CR, K5CY - (float)R4.y0, bufA, bufB, R5.x0, R5.y0);
    __syncthreads();
    // stage 6 (shear): bufB(R5) -> global tiles
    {
        #pragma unroll
        for (int k = 0; k < (TS * TS) / NT; ++k)
            s6_eval<INT>(tid + k * NT, bufB, go, tx0, ty0, R5.x0, R5.y0);
    }
}

// Compose the 6 nearest-neighbor integer maps (exact vs sequential resampling).
__global__ void compose_nearest_map(int* __restrict__ map) {
    int p = blockIdx.x * blockDim.x + threadIdx.x;
    if (p >= HW) return;
    const float TH[6][6] = {
        { 1.0f,  0.05f, 0.0f,  -0.03f, 1.0f,  0.0f },   // shear
        { CR,    -SR,   0.0f,   SR,    CR,    0.0f },   // rotate
        { 0.9f,  0.0f,  0.0f,   0.0f,  0.9f,  0.0f },   // zoom
        { 1.1f,  0.0f,  0.0f,   0.0f,  0.95f, 0.0f },   // scale
        { 1.0f,  0.0f,  0.06f,  0.0f,  1.0f, -0.04f },  // translate
        { -1.0f, 0.0f,  0.0f,   0.0f,  1.0f,  0.0f },   // mirror
    };
    int cx = p & 511, cy = p >> 9;
    bool valid = true;
    #pragma unroll
    for (int s = 0; s < 6; ++s) {
        if (!valid) break;
        float x = (cx + 0.5f) * (2.0f / 512.0f) - 1.0f;
        float y = (cy + 0.5f) * (2.0f / 512.0f) - 1.0f;
        float gx = TH[s][0] * x + TH[s][1] * y + TH[s][2];
        float gy = TH[s][3] * x + TH[s][4] * y + TH[s][5];
        float ix = ((gx + 1.0f) * 512.0f - 1.0f) * 0.5f;
        float iy = ((gy + 1.0f) * 512.0f - 1.0f) * 0.5f;
        float xr = rintf(ix), yr = rintf(iy);
        if (xr < 0.0f || xr > 511.0f || yr < 0.0f || yr > 511.0f) valid = false;
        else { cx = (int)xr; cy = (int)yr; }
    }
    map[p] = valid ? (cy * 512 + cx) : -1;
}

// One block per (plane-pair, 32x32 tile): label gather + 6 fused img stages
// for 2 planes sharing all coordinate math, interleaved as float2 in LDS.
__global__ __launch_bounds__(NT, 8) void fused_all(
    const float* __restrict__ img, const float* __restrict__ lab,
    const int* __restrict__ map, float* __restrict__ oimg,
    float* __restrict__ olab)
{
    __shared__ float2 bufA[BUFA_SZ];
    __shared__ float2 bufB[BUFB_SZ];
    int tid = threadIdx.x;
    int b = blockIdx.x;
    int group = b >> 8, tile = b & 255;
    int tx0 = (tile & 15) * TS, ty0 = (tile >> 4) * TS;
    int pbase = group * P;
    const float* gin = img + pbase * HW;
    const float* lin = lab + pbase * HW;
    float* go = oimg + pbase * HW;
    float* lo = olab + pbase * HW;

    // ---- label tiles: one map read feeds both planes ----
    {
        #pragma unroll
        for (int k = 0; k < (TS * TS) / NT; ++k) {
            int ii = tid + k * NT;
            int gidx = (ty0 + (ii >> 5)) * 512 + tx0 + (ii & 31);
            int m = map[gidx];
            float v0 = (m >= 0) ? lin[m] : 0.f;
            float v1 = (m >= 0) ? lin[HW + m] : 0.f;
            __builtin_nontemporal_store(v0, &lo[gidx]);
            __builtin_nontemporal_store(v1, &lo[HW + gidx]);
        }
    }

    // ---- region chain (uniform across threads) ----
    Box R6 = {tx0, tx0 + TS - 1, ty0, ty0 + TS - 1};
    Box R5 = back_box(R6, 1.0f, 0.05f, -12.775f, -0.03f, 1.0f, 7.665f);   // shear
    R5.x1 = min(R5.x1, R5.x0 + W5 - 1); R5.y1 = min(R5.y1, R5.y0 + H5 - 1);
    Box R4 = back_box(R5, CR, -SR, K5CX, SR, CR, K5CY);                   // rotate
    R4.x1 = min(R4.x1, R4.x0 + W4 - 1); R4.y1 = min(R4.y1, R4.y0 + H4 - 1);
    Box R3 = back_box(R4, 0.9f, 0.0f, 25.55f, 0.0f, 0.9f, 25.55f);        // zoom
    R3.x1 = min(R3.x1, R3.x0 + W3 - 1); R3.y1 = min(R3.y1, R3.y0 + H3 - 1);
    Box R2 = back_box(R3, 1.1f, 0.0f, -25.55f, 0.0f, 0.95f, 12.775f);     // scale

    bool dead = (R2.x1 < 0 || R2.x0 > 511 || R2.y1 < 0 || R2.y0 > 511)
             || (R3.x1 < 0 || R3.x0 > 511 || R3.y1 < 0 || R3.y0 > 511)
             || (R4.x1 < 0 || R4.x0 > 511 || R4.y1 < 0 || R4.y0 > 511)
             || (R5.x1 < 0 || R5.x0 > 511 || R5.y1 < 0 || R5.y0 > 511);
    if (dead) {
        #pragma unroll
        for (int k = 0; k < (TS * TS) / NT; ++k) {
            int ii = tid + k * NT;
            int gidx = (ty0 + (ii >> 5)) * 512 + tx0 + (ii & 31);
            __builtin_nontemporal_store(0.f, &go[gidx]);
            __builtin_nontemporal_store(0.f, &go[HW + gidx]);
        }
        return;
    }

    // interior: every PADDED region cell has fully-valid taps & coords
    bool interior =
        R2.x0 >= 0 && R2.x0 + W2 - 1 <= 495 && R2.y0 >= 11 && R2.y0 + H2 - 1 <= 511 &&
        R3.x0 >= 0 && R3.x0 + W3 - 1 <= 511 && R3.y0 >= 0 && R3.y0 + H3 - 1 <= 511 &&
        R4.x0 >= 0 && R4.x0 + W4 - 1 <= 511 && R4.y0 >= 0 && R4.y0 + H4 - 1 <= 511 &&
        R5.x0 >= 0 && R5.x0 + W5 - 1 <= 511 && R5.y0 >= 0 && R5.y0 + H5 - 1 <= 511;

    if (interior)
        img_tile<true >(tid, gin, go, tx0, ty0, R2, R3, R4, R5, bufA, bufB);
    else
        img_tile<false>(tid, gin, go, tx0, ty0, R2, R3, R4, R5, bufA, bufB);
}

extern "C" void kernel_launch(void* const* d_in, const int* in_sizes, int n_in,
                              void* d_out, int out_size, void* d_ws, size_t ws_size,
                              hipStream_t stream) {
    const float* img_in = (const float*)d_in[0];
    const float* lab_in = (const float*)d_in[1];
    float* out_img = (float*)d_out;
    float* out_lab = (float*)d_out + TOTAL;
    int* map = (int*)d_ws;

    compose_nearest_map<<<(HW + 255) / 256, 256, 0, stream>>>(map);
    fused_all<<<NGROUP * 256, NT, 0, stream>>>(img_in, lab_in, map, out_img, out_lab);
}